// Round 5
// baseline (445.635 us; speedup 1.0000x reference)
//
#include <hip/hip_runtime.h>
#include <math.h>

#define NA 50000
#define NE 800000
#define FDIM 128
#define KDIM 64
#define NRI 3
#define NRA 2

typedef unsigned short ushort_t;
typedef unsigned int uint_t;
typedef __attribute__((ext_vector_type(8))) short short8v;
typedef __attribute__((ext_vector_type(4))) float f32x4;
typedef __attribute__((ext_vector_type(4))) unsigned short u16x4;

// ssp(x) = softplus(x) - ln2 via hardware v_exp_f32/v_log_f32.
__device__ __forceinline__ float ssp_f(float x) {
    float e = __expf(-fabsf(x));
    return fmaxf(x, 0.0f) + __logf(1.0f + e) - 0.69314718055994530942f;
}
__device__ __forceinline__ ushort_t f2bf(float x) {
    unsigned u = __float_as_uint(x);
    u += 0x7FFFu + ((u >> 16) & 1u);          // RNE
    return (ushort_t)(u >> 16);
}
__device__ __forceinline__ float bf2f(ushort_t h) {
    return __uint_as_float(((unsigned)h) << 16);
}
__device__ __forceinline__ f32x4 ssp4(f32x4 v) {
    f32x4 r;
    #pragma unroll
    for (int j = 0; j < 4; ++j) r[j] = ssp_f(v[j]);
    return r;
}
__device__ __forceinline__ u16x4 pack4(f32x4 v) {
    u16x4 p;
    #pragma unroll
    for (int j = 0; j < 4; ++j) p[j] = f2bf(v[j]);
    return p;
}

// ---------------------------------------------------------------------------
// Weight pre-convert (once): fp32 -> bf16 into ws.
// wbf layout (ushort offsets): Wdesc@0 (8192), Wi@8192, Wj@24576,
// chain@40960: [Wri1_0,Wri2_0,Wri1_1,Wri2_1,Wri1_2,Wri2_2,Wd,Wra1_0,Wra2_0,Wra1_1,Wra2_1]
// ---------------------------------------------------------------------------
__global__ __launch_bounds__(256) void k_wconv(
    const float* __restrict__ Wdesc, const float* __restrict__ Wi,
    const float* __restrict__ Wj,    const float* __restrict__ Wri1,
    const float* __restrict__ Wri2,  const float* __restrict__ Wd,
    const float* __restrict__ Wra1,  const float* __restrict__ Wra2,
    ushort_t* __restrict__ wbf)
{
    const int seg = blockIdx.y;
    const int idx = blockIdx.x * 2048 + threadIdx.x * 8;
    const float* s; ushort_t* d; int cnt;
    const int CH = 40960;
    switch (seg) {
    case 0: cnt = 8192;  if (idx >= cnt) return; s = Wdesc + idx; d = wbf + idx; break;
    case 1: cnt = 16384; if (idx >= cnt) return; s = Wi + idx;    d = wbf + 8192 + idx; break;
    case 2: cnt = 16384; if (idx >= cnt) return; s = Wj + idx;    d = wbf + 24576 + idx; break;
    case 3: { cnt = 3*16384; if (idx >= cnt) return; int k = idx/16384, o = idx - k*16384;
              s = Wri1 + idx; d = wbf + CH + (2*k)*16384 + o; break; }
    case 4: { cnt = 3*16384; if (idx >= cnt) return; int k = idx/16384, o = idx - k*16384;
              s = Wri2 + idx; d = wbf + CH + (2*k+1)*16384 + o; break; }
    case 5: cnt = 16384; if (idx >= cnt) return; s = Wd + idx; d = wbf + CH + 6*16384 + idx; break;
    case 6: { cnt = 2*16384; if (idx >= cnt) return; int k = idx/16384, o = idx - k*16384;
              s = Wra1 + idx; d = wbf + CH + (7+2*k)*16384 + o; break; }
    default:{ cnt = 2*16384; if (idx >= cnt) return; int k = idx/16384, o = idx - k*16384;
              s = Wra2 + idx; d = wbf + CH + (8+2*k)*16384 + o; break; }
    }
    #pragma unroll
    for (int j = 0; j < 8; ++j) d[j] = f2bf(s[j]);
}

// ---------------------------------------------------------------------------
// Per-atom segment starts
// ---------------------------------------------------------------------------
__global__ __launch_bounds__(256) void k_row_starts(
    const int* __restrict__ idx_i, int* __restrict__ row_start)
{
    int i = blockIdx.x * 256 + threadIdx.x;
    if (i > NA) return;
    if (i == NA) { row_start[NA] = NE; return; }
    int lo = 0, hi = NE;
    while (lo < hi) { int mid = (lo + hi) >> 1; if (idx_i[mid] < i) lo = mid + 1; else hi = mid; }
    row_start[i] = lo;
}

// ---------------------------------------------------------------------------
// Transposed-GEMM helpers. Wave w owns atoms {16w + lrow}; each lane holds
// features {16nf + 4kgrp + r} of its atom. C[row=W-row(feature)][col=act-row(atom)].
// ---------------------------------------------------------------------------
__device__ __forceinline__ void stage_w(const ushort_t* __restrict__ src,
                                        ushort_t (*wlds)[136], int t)
{
    const int r = t >> 1, c0 = (t & 1) * 64;
    const short8v* s = (const short8v*)(src + (size_t)r * FDIM + c0);
    #pragma unroll
    for (int q = 0; q < 8; ++q)
        *(short8v*)&wlds[r][c0 + q * 8] = s[q];
}

__device__ __forceinline__ void gemm_tile_T(
    const ushort_t (*actA)[136], const ushort_t (*wlds)[136],
    int w, int lrow, int kgrp, const float* __restrict__ bias, f32x4 acc[8])
{
    short8v bfr[4];
    #pragma unroll
    for (int ks = 0; ks < 4; ++ks)
        bfr[ks] = *(const short8v*)&actA[16 * w + lrow][ks * 32 + kgrp * 8];
    #pragma unroll
    for (int nf = 0; nf < 8; ++nf)
        acc[nf] = *(const f32x4*)(bias + 16 * nf + 4 * kgrp);
    #pragma unroll
    for (int nf = 0; nf < 8; ++nf)
        #pragma unroll
        for (int ks = 0; ks < 4; ++ks) {
            short8v av = *(const short8v*)&wlds[16 * nf + lrow][ks * 32 + kgrp * 8];
            acc[nf] = __builtin_amdgcn_mfma_f32_16x16x32_bf16(av, bfr[ks], acc[nf], 0, 0, 0);
        }
}

// act = ssp(v), packed b64 writes into this wave's own 16 rows
__device__ __forceinline__ void write_act_T(
    ushort_t (*actA)[136], int w, int lrow, int kgrp, const f32x4 v[8])
{
    #pragma unroll
    for (int nf = 0; nf < 8; ++nf)
        *(u16x4*)&actA[16 * w + lrow][16 * nf + 4 * kgrp] = pack4(ssp4(v[nf]));
}

// ---------------------------------------------------------------------------
// Node pre (MFMA, transposed): xi = ssp(ssp(feat)@Wi.T+bi) -> msg (f32)
//                              xja = ssp(ssp(feat)@Wj.T+bj) -> bf16
// ---------------------------------------------------------------------------
__global__ __launch_bounds__(256) void k_node_pre(
    const float* __restrict__ feat, const ushort_t* __restrict__ wbf,
    const float* __restrict__ bi, const float* __restrict__ bj,
    float* __restrict__ xi_out, ushort_t* __restrict__ xja_out)
{
    __shared__ ushort_t actA[64][136];
    __shared__ ushort_t wlds[128][136];
    const int t = threadIdx.x, lane = t & 63, w = t >> 6;
    const int lrow = lane & 15, kgrp = lane >> 4;
    const int atom = blockIdx.x * 64 + 16 * w + lrow;
    const bool ok = atom < NA;

    f32x4 v[8];
    #pragma unroll
    for (int nf = 0; nf < 8; ++nf)
        v[nf] = ok ? *(const f32x4*)(feat + (size_t)atom * FDIM + 16 * nf + 4 * kgrp)
                   : (f32x4){0.f, 0.f, 0.f, 0.f};
    write_act_T(actA, w, lrow, kgrp, v);
    __syncthreads();
    stage_w(wbf + 8192, wlds, t);
    __syncthreads();
    f32x4 acc[8];
    gemm_tile_T(actA, wlds, w, lrow, kgrp, bi, acc);
    if (ok)
        #pragma unroll
        for (int nf = 0; nf < 8; ++nf)
            *(f32x4*)(xi_out + (size_t)atom * FDIM + 16 * nf + 4 * kgrp) = ssp4(acc[nf]);
    __syncthreads();
    stage_w(wbf + 24576, wlds, t);
    __syncthreads();
    gemm_tile_T(actA, wlds, w, lrow, kgrp, bj, acc);
    if (ok)
        #pragma unroll
        for (int nf = 0; nf < 8; ++nf)
            *(u16x4*)(xja_out + (size_t)atom * FDIM + 16 * nf + 4 * kgrp) = pack4(ssp4(acc[nf]));
}

// ---------------------------------------------------------------------------
// Edge GEMM (transposed, LDS-free): g[e][f] = desc[e]@Wdesc[f] (bf16 out).
// Wdesc A-frags resident in 64 VGPRs/wave; 8 tiles of 16 edges per wave.
// Per-lane C frag = 4 consecutive features of one edge -> packed 8B stores.
// ---------------------------------------------------------------------------
__device__ __forceinline__ short8v pack8(const float* p) {
    short8v r;
    #pragma unroll
    for (int j = 0; j < 8; ++j) r[j] = (short)f2bf(p[j]);
    return r;
}

__global__ __launch_bounds__(256) void k_gemm_g(
    const float* __restrict__ desc, const ushort_t* __restrict__ wdbf,
    ushort_t* __restrict__ g, int nE)
{
    const int t = threadIdx.x, lane = t & 63, w = t >> 6;
    const int lrow = lane & 15, kgrp = lane >> 4;

    short8v a[8][2];
    #pragma unroll
    for (int nf = 0; nf < 8; ++nf)
        #pragma unroll
        for (int ks = 0; ks < 2; ++ks)
            a[nf][ks] = *(const short8v*)(wdbf + (size_t)(16 * nf + lrow) * KDIM
                                          + ks * 32 + kgrp * 8);

    const int tile0 = (blockIdx.x * 4 + w) * 8;
    for (int tt = 0; tt < 8; ++tt) {
        const int e0 = (tile0 + tt) * 16;
        if (e0 >= nE) return;                      // wave-uniform
        const int er = e0 + lrow;
        short8v b[2];
        if (er < nE) {
            #pragma unroll
            for (int ks = 0; ks < 2; ++ks) {
                const float* p = desc + (size_t)er * KDIM + ks * 32 + kgrp * 8;
                float tmp[8];
                *(float4*)(tmp)     = *(const float4*)p;
                *(float4*)(tmp + 4) = *(const float4*)(p + 4);
                b[ks] = pack8(tmp);
            }
        } else {
            b[0] = (short8v){0,0,0,0,0,0,0,0};
            b[1] = b[0];
        }
        f32x4 acc[8];
        #pragma unroll
        for (int nf = 0; nf < 8; ++nf) acc[nf] = (f32x4){0.f, 0.f, 0.f, 0.f};
        #pragma unroll
        for (int nf = 0; nf < 8; ++nf) {
            acc[nf] = __builtin_amdgcn_mfma_f32_16x16x32_bf16(a[nf][0], b[0], acc[nf], 0,0,0);
            acc[nf] = __builtin_amdgcn_mfma_f32_16x16x32_bf16(a[nf][1], b[1], acc[nf], 0,0,0);
        }
        if (er < nE)
            #pragma unroll
            for (int nf = 0; nf < 8; ++nf)
                *(u16x4*)(g + (size_t)er * FDIM + 16 * nf + 4 * kgrp) = pack4(acc[nf]);
    }
}

// ---------------------------------------------------------------------------
// Scatter: msg[i] += sum_seg g[e]*xja[idx_j[e]]  (wave per atom, grid-stride)
// ---------------------------------------------------------------------------
__global__ __launch_bounds__(256) void k_scatter(
    const ushort_t* __restrict__ g,
    const int* __restrict__ row_start,
    const int* __restrict__ idx_j,
    const ushort_t* __restrict__ xja,
    float* __restrict__ msg,
    int ce0, int ce1)
{
    const int t = threadIdx.x & 63, w = threadIdx.x >> 6;
    const uint_t* gp = (const uint_t*)g;
    const uint_t* xp = (const uint_t*)xja;
    for (int i = blockIdx.x * 4 + w; i < NA; i += gridDim.x * 4) {
        int s = row_start[i], e = row_start[i + 1];
        if (s < ce0) s = ce0;
        if (e > ce1) e = ce1;
        if (s >= e) continue;
        float a0 = 0.0f, a1 = 0.0f;
        for (int k = s; k < e; ++k) {
            int jj = idx_j[k];
            uint_t gv = gp[(size_t)(k - ce0) * 64 + t];
            uint_t xv = xp[(size_t)jj * 64 + t];
            a0 += __uint_as_float(gv << 16) * __uint_as_float(xv << 16);
            a1 += __uint_as_float(gv & 0xFFFF0000u) * __uint_as_float(xv & 0xFFFF0000u);
        }
        float2* mp = (float2*)&msg[(size_t)i * FDIM + 2 * t];
        float2 mv = *mp;
        mv.x += a0; mv.y += a1;
        *mp = mv;
    }
}

// ---------------------------------------------------------------------------
// Fallback fused edge kernel (tiny-ws only)
// ---------------------------------------------------------------------------
__global__ __launch_bounds__(128) void k_edge(
    const float* __restrict__ desc,
    const int* __restrict__ idx_i,
    const int* __restrict__ idx_j,
    const float* __restrict__ Wdesc,
    const ushort_t* __restrict__ xja,
    float* __restrict__ msg)
{
    const int i = blockIdx.x;
    const int t = threadIdx.x;
    int lo = 0, hi = NE;
    while (lo < hi) { int mid = (lo + hi) >> 1; if (idx_i[mid] < i) lo = mid + 1; else hi = mid; }
    int start = lo;
    hi = NE;
    while (lo < hi) { int mid = (lo + hi) >> 1; if (idx_i[mid] < i + 1) lo = mid + 1; else hi = mid; }
    int end = lo;
    start = __builtin_amdgcn_readfirstlane(start);
    end   = __builtin_amdgcn_readfirstlane(end);
    if (start >= end) return;
    float wreg[KDIM];
    #pragma unroll
    for (int q = 0; q < KDIM / 4; ++q) {
        float4 wv = *(const float4*)(Wdesc + (size_t)t * KDIM + 4 * q);
        wreg[4*q+0] = wv.x; wreg[4*q+1] = wv.y; wreg[4*q+2] = wv.z; wreg[4*q+3] = wv.w;
    }
    float acc = 0.0f;
    for (int e = start; e < end; ++e) {
        int jj = idx_j[e];
        const float* de = desc + (size_t)e * KDIM;
        float dot = 0.0f;
        #pragma unroll
        for (int q = 0; q < KDIM / 4; ++q) {
            float4 dv = *(const float4*)(de + 4 * q);
            dot += dv.x * wreg[4*q] + dv.y * wreg[4*q+1]
                 + dv.z * wreg[4*q+2] + dv.w * wreg[4*q+3];
        }
        acc += dot * bf2f(xja[(size_t)jj * FDIM + t]);
    }
    msg[(size_t)i * FDIM + t] += acc;
}

// ---------------------------------------------------------------------------
// Fused node chain (transposed): 3 residuals + outmix + 2 residuals.
// m carried as f32x4[8] per thread (atom fixed per lane, features packed).
// ---------------------------------------------------------------------------
__global__ __launch_bounds__(256) void k_chain(
    const float* __restrict__ msgp, const float* __restrict__ feat,
    const float* __restrict__ u, const ushort_t* __restrict__ wch,
    const float* __restrict__ bri1, const float* __restrict__ bri2,
    const float* __restrict__ bd,
    const float* __restrict__ bra1, const float* __restrict__ bra2,
    float* __restrict__ xout)
{
    __shared__ ushort_t actA[64][136];
    __shared__ ushort_t wlds[128][136];
    const int t = threadIdx.x, lane = t & 63, w = t >> 6;
    const int lrow = lane & 15, kgrp = lane >> 4;
    const int atom = blockIdx.x * 64 + 16 * w + lrow;
    const bool ok = atom < NA;

    f32x4 m[8], h[8], acc[8];
    #pragma unroll
    for (int nf = 0; nf < 8; ++nf)
        m[nf] = ok ? *(const f32x4*)(msgp + (size_t)atom * FDIM + 16 * nf + 4 * kgrp)
                   : (f32x4){0.f, 0.f, 0.f, 0.f};

    // --- 3 interaction residuals ---
    for (int k = 0; k < NRI; ++k) {
        write_act_T(actA, w, lrow, kgrp, m);
        __syncthreads();
        stage_w(wch + (size_t)(2 * k) * 16384, wlds, t);
        __syncthreads();
        gemm_tile_T(actA, wlds, w, lrow, kgrp, bri1 + k * FDIM, acc);
        #pragma unroll
        for (int nf = 0; nf < 8; ++nf) h[nf] = acc[nf];
        write_act_T(actA, w, lrow, kgrp, h);
        __syncthreads();
        stage_w(wch + (size_t)(2 * k + 1) * 16384, wlds, t);
        __syncthreads();
        gemm_tile_T(actA, wlds, w, lrow, kgrp, bri2 + k * FDIM, acc);
        #pragma unroll
        for (int nf = 0; nf < 8; ++nf) m[nf] += acc[nf];
    }

    // --- outmix: m = u*feat + ssp(m)@Wd.T + bd ---
    write_act_T(actA, w, lrow, kgrp, m);
    __syncthreads();
    stage_w(wch + (size_t)6 * 16384, wlds, t);
    __syncthreads();
    gemm_tile_T(actA, wlds, w, lrow, kgrp, bd, acc);
    #pragma unroll
    for (int nf = 0; nf < 8; ++nf) {
        f32x4 fv = ok ? *(const f32x4*)(feat + (size_t)atom * FDIM + 16 * nf + 4 * kgrp)
                      : (f32x4){0.f, 0.f, 0.f, 0.f};
        f32x4 uv = *(const f32x4*)(u + 16 * nf + 4 * kgrp);
        m[nf] = uv * fv + acc[nf];
    }

    // --- 2 atomic residuals ---
    for (int k = 0; k < NRA; ++k) {
        write_act_T(actA, w, lrow, kgrp, m);
        __syncthreads();
        stage_w(wch + (size_t)(7 + 2 * k) * 16384, wlds, t);
        __syncthreads();
        gemm_tile_T(actA, wlds, w, lrow, kgrp, bra1 + k * FDIM, acc);
        #pragma unroll
        for (int nf = 0; nf < 8; ++nf) h[nf] = acc[nf];
        write_act_T(actA, w, lrow, kgrp, h);
        __syncthreads();
        stage_w(wch + (size_t)(8 + 2 * k) * 16384, wlds, t);
        __syncthreads();
        gemm_tile_T(actA, wlds, w, lrow, kgrp, bra2 + k * FDIM, acc);
        #pragma unroll
        for (int nf = 0; nf < 8; ++nf) m[nf] += acc[nf];
    }

    if (ok)
        #pragma unroll
        for (int nf = 0; nf < 8; ++nf)
            *(f32x4*)(xout + (size_t)atom * FDIM + 16 * nf + 4 * kgrp) = m[nf];
}

// ---------------------------------------------------------------------------
extern "C" void kernel_launch(void* const* d_in, const int* in_sizes, int n_in,
                              void* d_out, int out_size, void* d_ws, size_t ws_size,
                              hipStream_t stream)
{
    const float* feat  = (const float*)d_in[0];
    const float* desc  = (const float*)d_in[1];
    const int*   idx_i = (const int*)d_in[2];
    const int*   idx_j = (const int*)d_in[3];
    const float* Wdesc = (const float*)d_in[4];
    const float* Wi    = (const float*)d_in[5];
    const float* bi    = (const float*)d_in[6];
    const float* Wj    = (const float*)d_in[7];
    const float* bj    = (const float*)d_in[8];
    const float* Wri1  = (const float*)d_in[9];
    const float* bri1  = (const float*)d_in[10];
    const float* Wri2  = (const float*)d_in[11];
    const float* bri2  = (const float*)d_in[12];
    const float* Wd    = (const float*)d_in[13];
    const float* bd    = (const float*)d_in[14];
    const float* u     = (const float*)d_in[15];
    const float* Wra1  = (const float*)d_in[16];
    const float* bra1  = (const float*)d_in[17];
    const float* Wra2  = (const float*)d_in[18];
    const float* bra2  = (const float*)d_in[19];

    char* wsp = (char*)d_ws;
    float* msg = (float*)wsp;
    size_t off = (size_t)NA * FDIM * sizeof(float);
    ushort_t* xja = (ushort_t*)(wsp + off);
    off += (size_t)NA * FDIM * sizeof(ushort_t);
    int* row_start = (int*)(wsp + off);
    off += (((size_t)(NA + 1) * sizeof(int)) + 255) & ~(size_t)255;
    ushort_t* wbf = (ushort_t*)(wsp + off);
    off += (((size_t)221184 * sizeof(ushort_t)) + 255) & ~(size_t)255;
    ushort_t* gbuf = (ushort_t*)(wsp + off);
    size_t avail = (ws_size > off) ? ws_size - off : 0;
    size_t max_chunk = (avail / ((size_t)FDIM * sizeof(ushort_t))) & ~(size_t)511;

    float* xout = (float*)d_out;
    const int nblk64 = (NA + 63) / 64;

    k_wconv<<<dim3(24, 8), 256, 0, stream>>>(Wdesc, Wi, Wj, Wri1, Wri2, Wd, Wra1, Wra2, wbf);
    k_row_starts<<<(NA + 256) / 256, 256, 0, stream>>>(idx_i, row_start);
    k_node_pre<<<nblk64, 256, 0, stream>>>(feat, wbf, bi, bj, msg, xja);

    if (max_chunk >= 512) {
        for (size_t ce0 = 0; ce0 < NE; ce0 += max_chunk) {
            size_t ce1 = ce0 + max_chunk; if (ce1 > NE) ce1 = NE;
            int n = (int)(ce1 - ce0);
            k_gemm_g<<<(n + 511) / 512, 256, 0, stream>>>(desc + ce0 * KDIM, wbf, gbuf, n);
            k_scatter<<<1024, 256, 0, stream>>>(gbuf, row_start, idx_j, xja, msg,
                                                (int)ce0, (int)ce1);
        }
    } else {
        k_edge<<<NA, 128, 0, stream>>>(desc, idx_i, idx_j, Wdesc, xja, msg);
    }

    k_chain<<<nblk64, 256, 0, stream>>>(msg, feat, u, wbf + 40960,
                                        bri1, bri2, bd, bra1, bra2, xout);
}

// Round 6
// 343.614 us; speedup vs baseline: 1.2969x; 1.2969x over previous
//
#include <hip/hip_runtime.h>
#include <math.h>

#define NA 50000
#define NE 800000
#define FDIM 128
#define KDIM 64
#define NRI 3
#define NRA 2

typedef unsigned short ushort_t;
typedef unsigned int uint_t;
typedef __attribute__((ext_vector_type(8))) short short8v;
typedef __attribute__((ext_vector_type(4))) float f32x4;
typedef __attribute__((ext_vector_type(4))) unsigned short u16x4;

// ssp(x) = softplus(x) - ln2 via hardware v_exp_f32/v_log_f32.
__device__ __forceinline__ float ssp_f(float x) {
    float e = __expf(-fabsf(x));
    return fmaxf(x, 0.0f) + __logf(1.0f + e) - 0.69314718055994530942f;
}
__device__ __forceinline__ ushort_t f2bf(float x) {
    unsigned u = __float_as_uint(x);
    u += 0x7FFFu + ((u >> 16) & 1u);          // RNE
    return (ushort_t)(u >> 16);
}
__device__ __forceinline__ float bf2f(ushort_t h) {
    return __uint_as_float(((unsigned)h) << 16);
}
__device__ __forceinline__ f32x4 ssp4(f32x4 v) {
    f32x4 r;
    #pragma unroll
    for (int j = 0; j < 4; ++j) r[j] = ssp_f(v[j]);
    return r;
}
__device__ __forceinline__ u16x4 pack4(f32x4 v) {
    u16x4 p;
    #pragma unroll
    for (int j = 0; j < 4; ++j) p[j] = f2bf(v[j]);
    return p;
}

// ---------------------------------------------------------------------------
// Weight pre-convert (once): fp32 -> bf16 into ws.
// wbf layout (ushort offsets): Wdesc@0 (8192), Wi@8192, Wj@24576,
// chain@40960: [Wri1_0,Wri2_0,Wri1_1,Wri2_1,Wri1_2,Wri2_2,Wd,Wra1_0,Wra2_0,Wra1_1,Wra2_1]
// ---------------------------------------------------------------------------
__global__ __launch_bounds__(256) void k_wconv(
    const float* __restrict__ Wdesc, const float* __restrict__ Wi,
    const float* __restrict__ Wj,    const float* __restrict__ Wri1,
    const float* __restrict__ Wri2,  const float* __restrict__ Wd,
    const float* __restrict__ Wra1,  const float* __restrict__ Wra2,
    ushort_t* __restrict__ wbf)
{
    const int seg = blockIdx.y;
    const int idx = blockIdx.x * 2048 + threadIdx.x * 8;
    const float* s; ushort_t* d; int cnt;
    const int CH = 40960;
    switch (seg) {
    case 0: cnt = 8192;  if (idx >= cnt) return; s = Wdesc + idx; d = wbf + idx; break;
    case 1: cnt = 16384; if (idx >= cnt) return; s = Wi + idx;    d = wbf + 8192 + idx; break;
    case 2: cnt = 16384; if (idx >= cnt) return; s = Wj + idx;    d = wbf + 24576 + idx; break;
    case 3: { cnt = 3*16384; if (idx >= cnt) return; int k = idx/16384, o = idx - k*16384;
              s = Wri1 + idx; d = wbf + CH + (2*k)*16384 + o; break; }
    case 4: { cnt = 3*16384; if (idx >= cnt) return; int k = idx/16384, o = idx - k*16384;
              s = Wri2 + idx; d = wbf + CH + (2*k+1)*16384 + o; break; }
    case 5: cnt = 16384; if (idx >= cnt) return; s = Wd + idx; d = wbf + CH + 6*16384 + idx; break;
    case 6: { cnt = 2*16384; if (idx >= cnt) return; int k = idx/16384, o = idx - k*16384;
              s = Wra1 + idx; d = wbf + CH + (7+2*k)*16384 + o; break; }
    default:{ cnt = 2*16384; if (idx >= cnt) return; int k = idx/16384, o = idx - k*16384;
              s = Wra2 + idx; d = wbf + CH + (8+2*k)*16384 + o; break; }
    }
    #pragma unroll
    for (int j = 0; j < 8; ++j) d[j] = f2bf(s[j]);
}

// ---------------------------------------------------------------------------
// Per-atom segment starts
// ---------------------------------------------------------------------------
__global__ __launch_bounds__(256) void k_row_starts(
    const int* __restrict__ idx_i, int* __restrict__ row_start)
{
    int i = blockIdx.x * 256 + threadIdx.x;
    if (i > NA) return;
    if (i == NA) { row_start[NA] = NE; return; }
    int lo = 0, hi = NE;
    while (lo < hi) { int mid = (lo + hi) >> 1; if (idx_i[mid] < i) lo = mid + 1; else hi = mid; }
    row_start[i] = lo;
}

// ---------------------------------------------------------------------------
// Transposed-GEMM helpers. Wave w owns atoms {16w + lrow}; each lane holds
// features {16nf + 4kgrp + r} of its atom. C[row=W-row(feature)][col=act-row(atom)].
// ---------------------------------------------------------------------------
__device__ __forceinline__ void stage_w(const ushort_t* __restrict__ src,
                                        ushort_t (*wlds)[136], int t)
{
    const int r = t >> 1, c0 = (t & 1) * 64;
    const short8v* s = (const short8v*)(src + (size_t)r * FDIM + c0);
    #pragma unroll
    for (int q = 0; q < 8; ++q)
        *(short8v*)&wlds[r][c0 + q * 8] = s[q];
}

__device__ __forceinline__ void gemm_tile_T(
    const ushort_t (*actA)[136], const ushort_t (*wlds)[136],
    int w, int lrow, int kgrp, const float* __restrict__ bias, f32x4 acc[8])
{
    short8v bfr[4];
    #pragma unroll
    for (int ks = 0; ks < 4; ++ks)
        bfr[ks] = *(const short8v*)&actA[16 * w + lrow][ks * 32 + kgrp * 8];
    #pragma unroll
    for (int nf = 0; nf < 8; ++nf)
        acc[nf] = *(const f32x4*)(bias + 16 * nf + 4 * kgrp);
    #pragma unroll
    for (int nf = 0; nf < 8; ++nf)
        #pragma unroll
        for (int ks = 0; ks < 4; ++ks) {
            short8v av = *(const short8v*)&wlds[16 * nf + lrow][ks * 32 + kgrp * 8];
            acc[nf] = __builtin_amdgcn_mfma_f32_16x16x32_bf16(av, bfr[ks], acc[nf], 0, 0, 0);
        }
}

// act = ssp(v), packed b64 writes into this wave's own 16 rows
__device__ __forceinline__ void write_act_T(
    ushort_t (*actA)[136], int w, int lrow, int kgrp, const f32x4 v[8])
{
    #pragma unroll
    for (int nf = 0; nf < 8; ++nf)
        *(u16x4*)&actA[16 * w + lrow][16 * nf + 4 * kgrp] = pack4(ssp4(v[nf]));
}

// ---------------------------------------------------------------------------
// Node pre (MFMA, transposed): xi = ssp(ssp(feat)@Wi.T+bi) -> msg (f32)
//                              xja = ssp(ssp(feat)@Wj.T+bj) -> bf16
// ---------------------------------------------------------------------------
__global__ __launch_bounds__(256) void k_node_pre(
    const float* __restrict__ feat, const ushort_t* __restrict__ wbf,
    const float* __restrict__ bi, const float* __restrict__ bj,
    float* __restrict__ xi_out, ushort_t* __restrict__ xja_out)
{
    __shared__ ushort_t actA[64][136];
    __shared__ ushort_t wlds[128][136];
    const int t = threadIdx.x, lane = t & 63, w = t >> 6;
    const int lrow = lane & 15, kgrp = lane >> 4;
    const int atom = blockIdx.x * 64 + 16 * w + lrow;
    const bool ok = atom < NA;

    f32x4 v[8];
    #pragma unroll
    for (int nf = 0; nf < 8; ++nf)
        v[nf] = ok ? *(const f32x4*)(feat + (size_t)atom * FDIM + 16 * nf + 4 * kgrp)
                   : (f32x4){0.f, 0.f, 0.f, 0.f};
    write_act_T(actA, w, lrow, kgrp, v);
    __syncthreads();
    stage_w(wbf + 8192, wlds, t);
    __syncthreads();
    f32x4 acc[8];
    gemm_tile_T(actA, wlds, w, lrow, kgrp, bi, acc);
    if (ok)
        #pragma unroll
        for (int nf = 0; nf < 8; ++nf)
            *(f32x4*)(xi_out + (size_t)atom * FDIM + 16 * nf + 4 * kgrp) = ssp4(acc[nf]);
    __syncthreads();
    stage_w(wbf + 24576, wlds, t);
    __syncthreads();
    gemm_tile_T(actA, wlds, w, lrow, kgrp, bj, acc);
    if (ok)
        #pragma unroll
        for (int nf = 0; nf < 8; ++nf)
            *(u16x4*)(xja_out + (size_t)atom * FDIM + 16 * nf + 4 * kgrp) = pack4(ssp4(acc[nf]));
}

// ---------------------------------------------------------------------------
// Edge GEMM + gather-multiply (fused): p[e][f] = (desc[e]@Wdesc[f]) * xja[idx_j[e]][f]
// Wdesc A-frags resident in 64 VGPRs/wave; 8 tiles of 16 edges per wave.
// Per-lane C frag = 4 consecutive features of one edge -> 8B gather + 8B store.
// ---------------------------------------------------------------------------
__device__ __forceinline__ short8v pack8(const float* p) {
    short8v r;
    #pragma unroll
    for (int j = 0; j < 8; ++j) r[j] = (short)f2bf(p[j]);
    return r;
}

__global__ __launch_bounds__(256) void k_gemm_p(
    const float* __restrict__ desc, const ushort_t* __restrict__ wdbf,
    const int* __restrict__ idx_j,       // chunk-shifted
    const ushort_t* __restrict__ xja,
    ushort_t* __restrict__ p, int nE)
{
    const int t = threadIdx.x, lane = t & 63, w = t >> 6;
    const int lrow = lane & 15, kgrp = lane >> 4;

    short8v a[8][2];
    #pragma unroll
    for (int nf = 0; nf < 8; ++nf)
        #pragma unroll
        for (int ks = 0; ks < 2; ++ks)
            a[nf][ks] = *(const short8v*)(wdbf + (size_t)(16 * nf + lrow) * KDIM
                                          + ks * 32 + kgrp * 8);

    const int tile0 = (blockIdx.x * 4 + w) * 8;
    for (int tt = 0; tt < 8; ++tt) {
        const int e0 = (tile0 + tt) * 16;
        if (e0 >= nE) return;                      // wave-uniform
        const int er = e0 + lrow;
        const bool ok = er < nE;
        short8v b[2];
        int jj = 0;
        if (ok) {
            jj = idx_j[er];
            #pragma unroll
            for (int ks = 0; ks < 2; ++ks) {
                const float* q = desc + (size_t)er * KDIM + ks * 32 + kgrp * 8;
                float tmp[8];
                *(float4*)(tmp)     = *(const float4*)q;
                *(float4*)(tmp + 4) = *(const float4*)(q + 4);
                b[ks] = pack8(tmp);
            }
        } else {
            b[0] = (short8v){0,0,0,0,0,0,0,0};
            b[1] = b[0];
        }
        f32x4 acc[8];
        #pragma unroll
        for (int nf = 0; nf < 8; ++nf) acc[nf] = (f32x4){0.f, 0.f, 0.f, 0.f};
        #pragma unroll
        for (int nf = 0; nf < 8; ++nf) {
            acc[nf] = __builtin_amdgcn_mfma_f32_16x16x32_bf16(a[nf][0], b[0], acc[nf], 0,0,0);
            acc[nf] = __builtin_amdgcn_mfma_f32_16x16x32_bf16(a[nf][1], b[1], acc[nf], 0,0,0);
        }
        if (ok) {
            #pragma unroll
            for (int nf = 0; nf < 8; ++nf) {
                u16x4 xv = *(const u16x4*)(xja + (size_t)jj * FDIM + 16 * nf + 4 * kgrp);
                f32x4 pr;
                #pragma unroll
                for (int j = 0; j < 4; ++j) pr[j] = acc[nf][j] * bf2f(xv[j]);
                *(u16x4*)(p + (size_t)er * FDIM + 16 * nf + 4 * kgrp) = pack4(pr);
            }
        }
    }
}

// ---------------------------------------------------------------------------
// Segmented sum (streaming, no gather): msg[i] += sum_{e in seg(i)} p[e]
// Block (1 wave) per atom; lane t holds features 2t, 2t+1. 4-way unrolled.
// ---------------------------------------------------------------------------
__global__ __launch_bounds__(64) void k_segsum(
    const ushort_t* __restrict__ p,
    const int* __restrict__ row_start,
    float* __restrict__ msg,
    int ce0, int ce1)
{
    const int i = blockIdx.x;
    const int t = threadIdx.x;
    int s = row_start[i], e = row_start[i + 1];
    if (s < ce0) s = ce0;
    if (e > ce1) e = ce1;
    if (s >= e) return;
    const uint_t* pp = (const uint_t*)p;
    int k = s - ce0, kend = e - ce0;
    float a0 = 0.f, a1 = 0.f, b0 = 0.f, b1 = 0.f;
    float c0 = 0.f, c1 = 0.f, d0 = 0.f, d1 = 0.f;
    for (; k + 4 <= kend; k += 4) {
        uint_t v0 = pp[(size_t)(k    ) * 64 + t];
        uint_t v1 = pp[(size_t)(k + 1) * 64 + t];
        uint_t v2 = pp[(size_t)(k + 2) * 64 + t];
        uint_t v3 = pp[(size_t)(k + 3) * 64 + t];
        a0 += __uint_as_float(v0 << 16); a1 += __uint_as_float(v0 & 0xFFFF0000u);
        b0 += __uint_as_float(v1 << 16); b1 += __uint_as_float(v1 & 0xFFFF0000u);
        c0 += __uint_as_float(v2 << 16); c1 += __uint_as_float(v2 & 0xFFFF0000u);
        d0 += __uint_as_float(v3 << 16); d1 += __uint_as_float(v3 & 0xFFFF0000u);
    }
    for (; k < kend; ++k) {
        uint_t v = pp[(size_t)k * 64 + t];
        a0 += __uint_as_float(v << 16); a1 += __uint_as_float(v & 0xFFFF0000u);
    }
    a0 = (a0 + b0) + (c0 + d0);
    a1 = (a1 + b1) + (c1 + d1);
    float2* mp = (float2*)&msg[(size_t)i * FDIM + 2 * t];
    float2 mv = *mp;
    mv.x += a0; mv.y += a1;
    *mp = mv;
}

// ---------------------------------------------------------------------------
// Fallback fused edge kernel (tiny-ws only)
// ---------------------------------------------------------------------------
__global__ __launch_bounds__(128) void k_edge(
    const float* __restrict__ desc,
    const int* __restrict__ idx_i,
    const int* __restrict__ idx_j,
    const float* __restrict__ Wdesc,
    const ushort_t* __restrict__ xja,
    float* __restrict__ msg)
{
    const int i = blockIdx.x;
    const int t = threadIdx.x;
    int lo = 0, hi = NE;
    while (lo < hi) { int mid = (lo + hi) >> 1; if (idx_i[mid] < i) lo = mid + 1; else hi = mid; }
    int start = lo;
    hi = NE;
    while (lo < hi) { int mid = (lo + hi) >> 1; if (idx_i[mid] < i + 1) lo = mid + 1; else hi = mid; }
    int end = lo;
    start = __builtin_amdgcn_readfirstlane(start);
    end   = __builtin_amdgcn_readfirstlane(end);
    if (start >= end) return;
    float wreg[KDIM];
    #pragma unroll
    for (int q = 0; q < KDIM / 4; ++q) {
        float4 wv = *(const float4*)(Wdesc + (size_t)t * KDIM + 4 * q);
        wreg[4*q+0] = wv.x; wreg[4*q+1] = wv.y; wreg[4*q+2] = wv.z; wreg[4*q+3] = wv.w;
    }
    float acc = 0.0f;
    for (int e = start; e < end; ++e) {
        int jj = idx_j[e];
        const float* de = desc + (size_t)e * KDIM;
        float dot = 0.0f;
        #pragma unroll
        for (int q = 0; q < KDIM / 4; ++q) {
            float4 dv = *(const float4*)(de + 4 * q);
            dot += dv.x * wreg[4*q] + dv.y * wreg[4*q+1]
                 + dv.z * wreg[4*q+2] + dv.w * wreg[4*q+3];
        }
        acc += dot * bf2f(xja[(size_t)jj * FDIM + t]);
    }
    msg[(size_t)i * FDIM + t] += acc;
}

// ---------------------------------------------------------------------------
// Fused node chain (transposed): 3 residuals + outmix + 2 residuals.
// m carried as f32x4[8] per thread (atom fixed per lane, features packed).
// ---------------------------------------------------------------------------
__global__ __launch_bounds__(256) void k_chain(
    const float* __restrict__ msgp, const float* __restrict__ feat,
    const float* __restrict__ u, const ushort_t* __restrict__ wch,
    const float* __restrict__ bri1, const float* __restrict__ bri2,
    const float* __restrict__ bd,
    const float* __restrict__ bra1, const float* __restrict__ bra2,
    float* __restrict__ xout)
{
    __shared__ ushort_t actA[64][136];
    __shared__ ushort_t wlds[128][136];
    const int t = threadIdx.x, lane = t & 63, w = t >> 6;
    const int lrow = lane & 15, kgrp = lane >> 4;
    const int atom = blockIdx.x * 64 + 16 * w + lrow;
    const bool ok = atom < NA;

    f32x4 m[8], h[8], acc[8];
    #pragma unroll
    for (int nf = 0; nf < 8; ++nf)
        m[nf] = ok ? *(const f32x4*)(msgp + (size_t)atom * FDIM + 16 * nf + 4 * kgrp)
                   : (f32x4){0.f, 0.f, 0.f, 0.f};

    // --- 3 interaction residuals ---
    for (int k = 0; k < NRI; ++k) {
        write_act_T(actA, w, lrow, kgrp, m);
        __syncthreads();
        stage_w(wch + (size_t)(2 * k) * 16384, wlds, t);
        __syncthreads();
        gemm_tile_T(actA, wlds, w, lrow, kgrp, bri1 + k * FDIM, acc);
        #pragma unroll
        for (int nf = 0; nf < 8; ++nf) h[nf] = acc[nf];
        write_act_T(actA, w, lrow, kgrp, h);
        __syncthreads();
        stage_w(wch + (size_t)(2 * k + 1) * 16384, wlds, t);
        __syncthreads();
        gemm_tile_T(actA, wlds, w, lrow, kgrp, bri2 + k * FDIM, acc);
        #pragma unroll
        for (int nf = 0; nf < 8; ++nf) m[nf] += acc[nf];
    }

    // --- outmix: m = u*feat + ssp(m)@Wd.T + bd ---
    write_act_T(actA, w, lrow, kgrp, m);
    __syncthreads();
    stage_w(wch + (size_t)6 * 16384, wlds, t);
    __syncthreads();
    gemm_tile_T(actA, wlds, w, lrow, kgrp, bd, acc);
    #pragma unroll
    for (int nf = 0; nf < 8; ++nf) {
        f32x4 fv = ok ? *(const f32x4*)(feat + (size_t)atom * FDIM + 16 * nf + 4 * kgrp)
                      : (f32x4){0.f, 0.f, 0.f, 0.f};
        f32x4 uv = *(const f32x4*)(u + 16 * nf + 4 * kgrp);
        m[nf] = uv * fv + acc[nf];
    }

    // --- 2 atomic residuals ---
    for (int k = 0; k < NRA; ++k) {
        write_act_T(actA, w, lrow, kgrp, m);
        __syncthreads();
        stage_w(wch + (size_t)(7 + 2 * k) * 16384, wlds, t);
        __syncthreads();
        gemm_tile_T(actA, wlds, w, lrow, kgrp, bra1 + k * FDIM, acc);
        #pragma unroll
        for (int nf = 0; nf < 8; ++nf) h[nf] = acc[nf];
        write_act_T(actA, w, lrow, kgrp, h);
        __syncthreads();
        stage_w(wch + (size_t)(8 + 2 * k) * 16384, wlds, t);
        __syncthreads();
        gemm_tile_T(actA, wlds, w, lrow, kgrp, bra2 + k * FDIM, acc);
        #pragma unroll
        for (int nf = 0; nf < 8; ++nf) m[nf] += acc[nf];
    }

    if (ok)
        #pragma unroll
        for (int nf = 0; nf < 8; ++nf)
            *(f32x4*)(xout + (size_t)atom * FDIM + 16 * nf + 4 * kgrp) = m[nf];
}

// ---------------------------------------------------------------------------
extern "C" void kernel_launch(void* const* d_in, const int* in_sizes, int n_in,
                              void* d_out, int out_size, void* d_ws, size_t ws_size,
                              hipStream_t stream)
{
    const float* feat  = (const float*)d_in[0];
    const float* desc  = (const float*)d_in[1];
    const int*   idx_i = (const int*)d_in[2];
    const int*   idx_j = (const int*)d_in[3];
    const float* Wdesc = (const float*)d_in[4];
    const float* Wi    = (const float*)d_in[5];
    const float* bi    = (const float*)d_in[6];
    const float* Wj    = (const float*)d_in[7];
    const float* bj    = (const float*)d_in[8];
    const float* Wri1  = (const float*)d_in[9];
    const float* bri1  = (const float*)d_in[10];
    const float* Wri2  = (const float*)d_in[11];
    const float* bri2  = (const float*)d_in[12];
    const float* Wd    = (const float*)d_in[13];
    const float* bd    = (const float*)d_in[14];
    const float* u     = (const float*)d_in[15];
    const float* Wra1  = (const float*)d_in[16];
    const float* bra1  = (const float*)d_in[17];
    const float* Wra2  = (const float*)d_in[18];
    const float* bra2  = (const float*)d_in[19];

    char* wsp = (char*)d_ws;
    float* msg = (float*)wsp;
    size_t off = (size_t)NA * FDIM * sizeof(float);
    ushort_t* xja = (ushort_t*)(wsp + off);
    off += (size_t)NA * FDIM * sizeof(ushort_t);
    int* row_start = (int*)(wsp + off);
    off += (((size_t)(NA + 1) * sizeof(int)) + 255) & ~(size_t)255;
    ushort_t* wbf = (ushort_t*)(wsp + off);
    off += (((size_t)221184 * sizeof(ushort_t)) + 255) & ~(size_t)255;
    ushort_t* gbuf = (ushort_t*)(wsp + off);
    size_t avail = (ws_size > off) ? ws_size - off : 0;
    size_t max_chunk = (avail / ((size_t)FDIM * sizeof(ushort_t))) & ~(size_t)511;

    float* xout = (float*)d_out;
    const int nblk64 = (NA + 63) / 64;

    k_wconv<<<dim3(24, 8), 256, 0, stream>>>(Wdesc, Wi, Wj, Wri1, Wri2, Wd, Wra1, Wra2, wbf);
    k_row_starts<<<(NA + 256) / 256, 256, 0, stream>>>(idx_i, row_start);
    k_node_pre<<<nblk64, 256, 0, stream>>>(feat, wbf, bi, bj, msg, xja);

    if (max_chunk >= 512) {
        for (size_t ce0 = 0; ce0 < NE; ce0 += max_chunk) {
            size_t ce1 = ce0 + max_chunk; if (ce1 > NE) ce1 = NE;
            int n = (int)(ce1 - ce0);
            k_gemm_p<<<(n + 511) / 512, 256, 0, stream>>>(desc + ce0 * KDIM, wbf,
                                                          idx_j + ce0, xja, gbuf, n);
            k_segsum<<<NA, 64, 0, stream>>>(gbuf, row_start, msg, (int)ce0, (int)ce1);
        }
    } else {
        k_edge<<<NA, 128, 0, stream>>>(desc, idx_i, idx_j, Wdesc, xja, msg);
    }

    k_chain<<<nblk64, 256, 0, stream>>>(msg, feat, u, wbf + 40960,
                                        bri1, bri2, bd, bra1, bra2, xout);
}